// Round 3
// baseline (638.864 us; speedup 1.0000x reference)
//
#include <hip/hip_runtime.h>

// B=1024, N=128, D=256, H=4, C=64, H*C=256
#define BB 1024
#define NP1 129

typedef _Float16 f16;
typedef _Float16 f16x4 __attribute__((ext_vector_type(4)));
typedef _Float16 f16x8 __attribute__((ext_vector_type(8)));
typedef float f32x4 __attribute__((ext_vector_type(4)));

// ws layout (f16 elements):
//   [0)      WqT  [256][256]  WqT[hc][d] = Wq[d][hc]
//   [65536)  WsT  [256][256]  WsT[hc][d] = Ws[d][hc]
//   [131072) Wk16 [256][256]  plain cast of Wk
//   [196608) We16 [256][256]  plain cast of We
//   [262144) WvWeT[256][512]  WvWeT[col][k] = k<256 ? Wv[k][col] : We[k-256][col]
// total 393216 f16 = 786432 bytes
#define WS_WQT 0
#define WS_WST 65536
#define WS_WK 131072
#define WS_WE 196608
#define WS_WVWET 262144

__global__ __launch_bounds__(512) void pack_w(
    const float* __restrict__ Wq, const float* __restrict__ Wk,
    const float* __restrict__ Wv, const float* __restrict__ We,
    const float* __restrict__ Ws, f16* __restrict__ ws) {
  int idx = blockIdx.x * 512 + threadIdx.x;  // 0..393215
  if (idx < 262144) {
    int m = idx >> 16;
    int r = (idx >> 8) & 255;
    int c = idx & 255;
    float v;
    if (m == 0) v = Wq[c * 256 + r];        // WqT[hc=r][d=c]
    else if (m == 1) v = Ws[c * 256 + r];   // WsT[hc=r][d=c]
    else if (m == 2) v = Wk[r * 256 + c];   // Wk16 plain
    else v = We[r * 256 + c];               // We16 plain
    ws[idx] = (f16)v;
  } else {
    int j = idx - 262144;
    int col = j >> 9;
    int k = j & 511;
    float v = (k < 256) ? Wv[k * 256 + col] : We[(k - 256) * 256 + col];
    ws[WS_WVWET + j] = (f16)v;
  }
}

// lgkm-only barrier: does NOT drain vmcnt, so prefetched global loads stay in flight.
__device__ __forceinline__ void barrier_lgkm() {
  asm volatile("s_waitcnt lgkmcnt(0)" ::: "memory");
  __builtin_amdgcn_sched_barrier(0);
  __builtin_amdgcn_s_barrier();
  __builtin_amdgcn_sched_barrier(0);
}

// padded u layout: bank-spread across h (x546) and k-quarter (x136)
__device__ __forceinline__ int uaddr(int h, int k) {
  return h * 546 + (k >> 7) * 136 + (k & 127);
}

#define ISSUE(cc, RX, RE)                                            \
  do {                                                               \
    _Pragma("unroll") for (int j = 0; j < 4; ++j) {                  \
      int fid = t + j * 512;                                         \
      int row = fid >> 6;                                            \
      int c4 = fid & 63;                                             \
      RX[j] = *(const float4*)(xg + (32 * (cc) + row) * 256 + c4 * 4); \
      RE[j] = *(const float4*)(eg + (32 * (cc) + row) * 256 + c4 * 4); \
    }                                                                \
  } while (0)

#define WRITE(cc, RX, RE)                                            \
  do {                                                               \
    _Pragma("unroll") for (int j = 0; j < 4; ++j) {                  \
      int fid = t + j * 512;                                         \
      int row = fid >> 6;                                            \
      int c4 = fid & 63;                                             \
      int s = (row & 7) << 3;                                        \
      int kx = (c4 * 4) ^ s;                                         \
      int ke = (256 + c4 * 4) ^ s;                                   \
      f16x4 hx, he;                                                  \
      hx[0] = (f16)RX[j].x; hx[1] = (f16)RX[j].y;                    \
      hx[2] = (f16)RX[j].z; hx[3] = (f16)RX[j].w;                    \
      he[0] = (f16)RE[j].x; he[1] = (f16)RE[j].y;                    \
      he[2] = (f16)RE[j].z; he[3] = (f16)RE[j].w;                    \
      *(f16x4*)&xe[(32 * (cc) + row) * 512 + kx] = hx;               \
      *(f16x4*)&xe[(32 * (cc) + row) * 512 + ke] = he;               \
    }                                                                \
  } while (0)

// One block per batch element. 512 threads = 8 waves (2m x 4n for skip-GEMM).
// Attention GEMMs eliminated: scores via u-vectors, agg via z = alpha @ xe.
__global__ __launch_bounds__(512, 2) void fused_gtn(
    const float* __restrict__ central, const float* __restrict__ neigh,
    const float* __restrict__ edge, const float* __restrict__ bq,
    const float* __restrict__ bv, const float* __restrict__ bskip,
    const f16* __restrict__ ws, float* __restrict__ out) {
  __shared__ __align__(16) f16 xe[128 * 512];       // 128 KiB, XOR-swizzled rows
  __shared__ __align__(16) float u_lds[2176];       // padded [4][512]
  __shared__ __align__(16) float c_lds[256];
  __shared__ __align__(16) float q_lds[256];
  __shared__ __align__(16) float sc[4 * 128];       // [h][n]
  __shared__ __align__(16) float alphaT[128 * 4];   // [n][h]
  __shared__ __align__(16) float z_lds[4 * 512];    // [h][k]
  __shared__ float aggbuf[256];
  __shared__ float skipc[256];

  const int b = blockIdx.x;
  const int t = threadIdx.x;
  const int w = t >> 6, l = t & 63;
  const int wm = w >> 2, wn = w & 3;
  const int l15 = l & 15, l4 = l >> 4;

  const f16* WqT = ws + WS_WQT;
  const f16* WsT = ws + WS_WST;
  const f16* Wk16 = ws + WS_WK;
  const f16* We16 = ws + WS_WE;
  const f16* WvWeT = ws + WS_WVWET;

  const float* xg = neigh + (size_t)b * (128 * 256);
  const float* eg = edge + (size_t)b * (128 * 256);

  // -------- prefetch chunks 0,1 into registers (issue-early) --------
  float4 rxA[4], reA[4], rxB[4], reB[4];
  ISSUE(0, rxA, reA);
  ISSUE(1, rxB, reB);

  // -------- preload skip-GEMM B-fragments (held in regs all kernel) --------
  f16x8 Bs[4][8];
  float bskip_r[4];
#pragma unroll
  for (int nf = 0; nf < 4; ++nf) {
    int col = 64 * wn + 16 * nf + l15;
    bskip_r[nf] = bskip[col];
#pragma unroll
    for (int ks = 0; ks < 8; ++ks)
      Bs[nf][ks] = *(const f16x8*)(WsT + col * 256 + ks * 32 + l4 * 8);
  }

  if (t < 256) {
    c_lds[t] = central[b * 256 + t];
    aggbuf[t] = 0.f;
  }
  barrier_lgkm();

  // -------- q (t<256) / skip_c (t>=256) GEMVs --------
  {
    int hc = t & 255;
    const f16* wrow = (t < 256) ? (WqT + hc * 256) : (WsT + hc * 256);
    float acc = 0.f;
#pragma unroll
    for (int j2 = 0; j2 < 32; ++j2) {
      f16x8 wv = *(const f16x8*)(wrow + j2 * 8);
      const float* cp = c_lds + j2 * 8;
#pragma unroll
      for (int u = 0; u < 8; ++u) acc += cp[u] * (float)wv[u];
    }
    if (t < 256) q_lds[hc] = acc + bq[hc];
    else skipc[hc] = acc + bskip[hc];
  }
  barrier_lgkm();

  // -------- u_k/u_e: u[h][k] = sum_c q[h,c] * W[k][h*64+c]  (4 dots/thread) ----
  {
#pragma unroll
    for (int r = 0; r < 4; ++r) {
      int idx = t + r * 512;
      int mat = idx >> 10, h = (idx >> 8) & 3, d = idx & 255;
      const f16* wp = (mat == 0 ? Wk16 : We16) + d * 256 + h * 64;
      const float* qp = q_lds + h * 64;
      float acc = 0.f;
#pragma unroll
      for (int j2 = 0; j2 < 8; ++j2) {
        f16x8 wv = *(const f16x8*)(wp + j2 * 8);
#pragma unroll
        for (int u = 0; u < 8; ++u) acc += qp[j2 * 8 + u] * (float)wv[u];
      }
      u_lds[uaddr(h, mat * 256 + d)] = acc;
    }
  }

  // -------- pipelined chunk loop: write chunk, prefetch +2, compute ----------
  auto compute = [&](int cc) {
    // scores for this chunk's 32 rows: t -> (quarter, head, local row)
    {
      int qtr = t & 3, h = (t >> 2) & 3, nl = t >> 4;
      int row = 32 * cc + nl;
      int s = (row & 7) << 3;
      const f16* xrow = xe + row * 512;
      const float* up = u_lds + h * 546 + qtr * 136;
      float acc = 0.f;
#pragma unroll
      for (int j2 = 0; j2 < 16; ++j2) {
        int k0 = qtr * 128 + j2 * 8;
        f16x8 xv = *(const f16x8*)&xrow[k0 ^ s];
#pragma unroll
        for (int u = 0; u < 8; ++u) acc += (float)xv[u] * up[j2 * 8 + u];
      }
      acc += __shfl_xor(acc, 1);
      acc += __shfl_xor(acc, 2);
      if (qtr == 0) sc[h * 128 + row] = acc * 0.125f;
    }
    // skip-GEMM: 32 rows x 256 cols, wave tile 16x64, B in registers
    {
      f32x4 accS[4] = {};
#pragma unroll
      for (int ks = 0; ks < 8; ++ks) {
        int row = 32 * cc + 16 * wm + l15;
        f16x8 a = *(const f16x8*)&xe[row * 512 + ((ks * 32 + l4 * 8) ^ ((row & 7) << 3))];
#pragma unroll
        for (int nf = 0; nf < 4; ++nf)
          accS[nf] = __builtin_amdgcn_mfma_f32_16x16x32_f16(a, Bs[nf][ks], accS[nf], 0, 0, 0);
      }
#pragma unroll
      for (int nf = 0; nf < 4; ++nf) {
        int col = 64 * wn + 16 * nf + l15;
#pragma unroll
        for (int i = 0; i < 4; ++i) {
          int grow = 32 * cc + 16 * wm + 4 * l4 + i;
          out[((size_t)b * NP1 + 1 + grow) * 256 + col] = accS[nf][i] + bskip_r[nf];
        }
      }
    }
  };

  WRITE(0, rxA, reA); ISSUE(2, rxA, reA); barrier_lgkm(); compute(0);
  WRITE(1, rxB, reB); ISSUE(3, rxB, reB); barrier_lgkm(); compute(1);
  WRITE(2, rxA, reA);                     barrier_lgkm(); compute(2);
  WRITE(3, rxB, reB);                     barrier_lgkm(); compute(3);

  barrier_lgkm();

  // -------- softmax over n (waves 0..3, h = w) -> alphaT[n][h] --------
  if (w < 4) {
    float s0 = sc[w * 128 + l], s1 = sc[w * 128 + 64 + l];
    float m = fmaxf(s0, s1);
#pragma unroll
    for (int off = 32; off >= 1; off >>= 1) m = fmaxf(m, __shfl_xor(m, off));
    float p0 = __expf(s0 - m), p1 = __expf(s1 - m);
    float sum = p0 + p1;
#pragma unroll
    for (int off = 32; off >= 1; off >>= 1) sum += __shfl_xor(sum, off);
    float inv = 1.f / sum;
    alphaT[l * 4 + w] = p0 * inv;
    alphaT[(64 + l) * 4 + w] = p1 * inv;
  }
  barrier_lgkm();

  // -------- z[h][k] = sum_n alpha[h][n]*xe[n][k]  (thread t = k) --------
  {
    float z0 = 0.f, z1 = 0.f, z2 = 0.f, z3 = 0.f;
    for (int n = 0; n < 128; ++n) {
      float4 al = *(const float4*)&alphaT[n * 4];  // broadcast
      float xv = (float)xe[n * 512 + (t ^ ((n & 7) << 3))];
      z0 += al.x * xv; z1 += al.y * xv; z2 += al.z * xv; z3 += al.w * xv;
    }
    z_lds[t] = z0; z_lds[512 + t] = z1; z_lds[1024 + t] = z2; z_lds[1536 + t] = z3;
  }
  barrier_lgkm();

  // -------- agg[col] = sum_k z[h][k]*WvWeT[col][k]  (2 threads/col) --------
  {
    int col = t & 255, hf = t >> 8, h = col >> 6;
    const f16* wrow = WvWeT + col * 512 + hf * 256;
    const float* zrow = z_lds + h * 512 + hf * 256;
    float acc = 0.f;
#pragma unroll
    for (int j2 = 0; j2 < 32; ++j2) {
      f16x8 wv = *(const f16x8*)(wrow + j2 * 8);
#pragma unroll
      for (int u = 0; u < 8; ++u) acc += zrow[j2 * 8 + u] * (float)wv[u];
    }
    atomicAdd(&aggbuf[col], acc);
  }
  barrier_lgkm();

  // -------- central row: skip_c + agg + bv (sum alpha = 1; bk cancels) --------
  if (t < 256) {
    out[(size_t)b * NP1 * 256 + t] = skipc[t] + aggbuf[t] + bv[t];
  }
}

extern "C" void kernel_launch(void* const* d_in, const int* in_sizes, int n_in,
                              void* d_out, int out_size, void* d_ws, size_t ws_size,
                              hipStream_t stream) {
  (void)in_sizes; (void)n_in; (void)out_size; (void)ws_size;
  const float* central = (const float*)d_in[0];
  const float* neigh   = (const float*)d_in[1];
  const float* edge    = (const float*)d_in[2];
  const float* Wq      = (const float*)d_in[3];
  const float* bq      = (const float*)d_in[4];
  const float* Wk      = (const float*)d_in[5];
  const float* Wv      = (const float*)d_in[7];
  const float* bv      = (const float*)d_in[8];
  const float* We      = (const float*)d_in[9];
  const float* Ws      = (const float*)d_in[10];
  const float* bsk     = (const float*)d_in[11];
  f16* ws = (f16*)d_ws;  // 786432 bytes
  float* out = (float*)d_out;

  pack_w<<<768, 512, 0, stream>>>(Wq, Wk, Wv, We, Ws, ws);
  fused_gtn<<<BB, 512, 0, stream>>>(central, neigh, edge, bq, bv, bsk, ws, out);
}